// Round 1
// baseline (737.824 us; speedup 1.0000x reference)
//
#include <hip/hip_runtime.h>
#include <math.h>

#define B_ 128
#define D_ 128
#define P_ 4
#define M_ 100000
#define K_ 10
#define SCALE_ 10.0f

// ---------- reduction helpers ----------
__device__ inline float waveReduceSum(float v) {
    #pragma unroll
    for (int off = 32; off > 0; off >>= 1) v += __shfl_xor(v, off, 64);
    return v;
}

// 128-thread block reduce; result broadcast to all threads
__device__ inline float blockReduce128(float v, float* sh2) {
    v = waveReduceSum(v);
    int wid = threadIdx.x >> 6;
    if ((threadIdx.x & 63) == 0) sh2[wid] = v;
    __syncthreads();
    float r = sh2[0] + sh2[1];
    __syncthreads();
    return r;
}

// ---------- init: mask=1, s_neg=0 ----------
__global__ void k_init(unsigned char* mask, float* s_neg) {
    int i = blockIdx.x * 256 + threadIdx.x;
    if (i < M_) mask[i] = 1;
    if (i < P_ * B_) s_neg[i] = 0.f;
}

// ---------- scatter zeros into mask ----------
__global__ void k_scatter(const int* __restrict__ ci, const int* __restrict__ pos,
                          unsigned char* mask) {
    int i = blockIdx.x * 256 + threadIdx.x;
    if (i < B_ * K_) mask[ci[i]] = 0;
    else if (i < B_ * K_ + B_) mask[pos[i - B_ * K_]] = 0;
}

// ---------- normalize rows of img/txt, write a2 = sum(n^2) ----------
__global__ __launch_bounds__(128) void k_norm(const float* __restrict__ img,
                                              const float* __restrict__ txt,
                                              float* img_n, float* txt_n,
                                              float* a2i, float* a2t) {
    __shared__ float sh2[2];
    int row = blockIdx.x & 127, which = blockIdx.x >> 7;
    int t = threadIdx.x;
    const float* src = which ? txt : img;
    float* dst = which ? txt_n : img_n;
    float* a2  = which ? a2t : a2i;
    float v = src[row * D_ + t];
    float s = blockReduce128(v * v, sh2);
    float n = v / sqrtf(s);
    dst[row * D_ + t] = n;
    float s2 = blockReduce128(n * n, sh2);
    if (t == 0) a2[row] = s2;
}

// ---------- MMD: block i handles row i of kxx/kyy/kxy ----------
__global__ __launch_bounds__(128) void k_mmd(const float* __restrict__ img_n,
                                             const float* __restrict__ txt_n,
                                             const float* __restrict__ a2i,
                                             const float* __restrict__ a2t,
                                             double* __restrict__ mmd_part) {
    __shared__ float ri[D_], rt[D_];
    __shared__ float sh2[2];
    int i = blockIdx.x, j = threadIdx.x;
    ri[j] = img_n[i * D_ + j];
    rt[j] = txt_n[i * D_ + j];
    __syncthreads();
    const float* aj = img_n + j * D_;
    const float* bj = txt_n + j * D_;
    float dxx = 0.f, dyy = 0.f, dxy = 0.f;
    #pragma unroll 4
    for (int d = 0; d < D_; d++) {
        float av = aj[d], bv = bj[d];
        dxx = fmaf(ri[d], av, dxx);
        dyy = fmaf(rt[d], bv, dyy);
        dxy = fmaf(ri[d], bv, dxy);
    }
    float kxx = (i == j) ? 0.f : expf(-fmaxf(a2i[i] + a2i[j] - 2.f * dxx, 0.f) * 0.5f);
    float kyy = (i == j) ? 0.f : expf(-fmaxf(a2t[i] + a2t[j] - 2.f * dyy, 0.f) * 0.5f);
    float kxy = expf(-fmaxf(a2i[i] + a2t[j] - 2.f * dxy, 0.f) * 0.5f);
    float sxx = blockReduce128(kxx, sh2);
    float syy = blockReduce128(kyy, sh2);
    float sxy = blockReduce128(kxy, sh2);
    if (j == 0) {
        mmd_part[i] = (double)sxx;
        mmd_part[128 + i] = (double)syy;
        mmd_part[256 + i] = (double)sxy;
    }
}

// ---------- pos part: one wave per (p,b); also writes f2 and pos_vid ----------
__global__ __launch_bounds__(64) void k_pos(const float* __restrict__ local,
                                            const float* __restrict__ centers,
                                            const int* __restrict__ ci,
                                            const int* __restrict__ memory_vid,
                                            float* f2w, float* s_pos, float* out) {
    int p = blockIdx.x >> 7, b = blockIdx.x & 127;
    int t = threadIdx.x;
    const float* f = local + ((size_t)p * B_ + b) * D_;
    float f0 = f[t], f1 = f[t + 64];
    float f2v = waveReduceSum(f0 * f0 + f1 * f1);
    if (t == 0) f2w[p * B_ + b] = f2v;
    float s = 0.f;
    for (int k = 0; k < K_; k++) {
        int idx = ci[b * K_ + k];
        const float* c = centers + ((size_t)p * M_ + idx) * D_;
        float c0 = c[t], c1 = c[t + 64];
        float p2 = waveReduceSum(c0 * c0 + c1 * c1);
        float fp = waveReduceSum(f0 * c0 + f1 * c1);
        float d2 = fmaxf(f2v + p2 - 2.f * fp, 0.f);
        s += expf(-SCALE_ * sqrtf(d2));
    }
    if (t == 0) s_pos[p * B_ + b] = s;
    if (p == 0 && t < K_) {
        int idx = ci[b * K_ + t];
        out[3 + b * K_ + t] = (float)memory_vid[idx];
    }
}

// ---------- neg part: 128b x 128m fp32 tile GEMM + fused exp epilogue ----------
#define TM_ 128
__global__ __launch_bounds__(256) void k_neg(const float* __restrict__ local,
                                             const float* __restrict__ centers,
                                             const float* __restrict__ f2w,
                                             const unsigned char* __restrict__ mask,
                                             float* __restrict__ s_neg) {
    const int p = blockIdx.y;
    const int m0 = blockIdx.x * TM_;
    const int t = threadIdx.x;
    const int tb = t >> 4;   // 0..15, b_i = tb + 16*i
    const int tm = t & 15;   // 0..15, m_j = tm + 16*j
    __shared__ float Ls[128 * 129];     // local [b][k], row pad +1
    __shared__ float Cs[128 * 33];      // centers chunk [m][kk], row pad +1
    __shared__ float c2part[128 * 8];
    __shared__ float c2s[128];
    __shared__ float sred[128 * 16];

    // stage local[p] (full 128x128) into LDS
    const float* lp = local + (size_t)p * B_ * D_;
    #pragma unroll
    for (int jj = 0; jj < 16; jj++) {
        int q = t + 256 * jj;          // float4 index 0..4095
        int b = q >> 5, kq = q & 31;
        const float4 v = *(const float4*)(lp + b * D_ + kq * 4);
        float* dst = &Ls[b * 129 + kq * 4];
        dst[0] = v.x; dst[1] = v.y; dst[2] = v.z; dst[3] = v.w;
    }

    float acc[8][8];
    #pragma unroll
    for (int i = 0; i < 8; i++)
        #pragma unroll
        for (int j = 0; j < 8; j++) acc[i][j] = 0.f;
    float c2p[4] = {0.f, 0.f, 0.f, 0.f};

    for (int kc = 0; kc < 4; kc++) {
        __syncthreads();
        // stage centers chunk [m0..m0+128) x [kc*32..+32)
        #pragma unroll
        for (int jj = 0; jj < 4; jj++) {
            int l = t + 256 * jj;       // float4 index 0..1023
            int mm = l >> 3, kq = l & 7;
            int gm = m0 + mm;
            float4 v = make_float4(0.f, 0.f, 0.f, 0.f);
            if (gm < M_) v = *(const float4*)(centers + ((size_t)p * M_ + gm) * D_ + kc * 32 + kq * 4);
            float* dst = &Cs[mm * 33 + kq * 4];
            dst[0] = v.x; dst[1] = v.y; dst[2] = v.z; dst[3] = v.w;
            c2p[jj] += v.x * v.x + v.y * v.y + v.z * v.z + v.w * v.w;
        }
        __syncthreads();
        #pragma unroll
        for (int kk = 0; kk < 32; kk++) {
            int k = kc * 32 + kk;
            float a[8], c[8];
            #pragma unroll
            for (int i = 0; i < 8; i++) a[i] = Ls[(tb + 16 * i) * 129 + k];
            #pragma unroll
            for (int j = 0; j < 8; j++) c[j] = Cs[(tm + 16 * j) * 33 + kk];
            #pragma unroll
            for (int i = 0; i < 8; i++)
                #pragma unroll
                for (int j = 0; j < 8; j++)
                    acc[i][j] = fmaf(a[i], c[j], acc[i][j]);
        }
    }

    // reduce c2 partials: c2part[l] holds partial for m=l/8, kq=l%8
    #pragma unroll
    for (int jj = 0; jj < 4; jj++) c2part[t + 256 * jj] = c2p[jj];
    __syncthreads();
    if (t < 128) {
        float s = 0.f;
        #pragma unroll
        for (int q = 0; q < 8; q++) s += c2part[t * 8 + q];
        c2s[t] = s;
    }
    __syncthreads();

    // epilogue: e = exp(-10*sqrt(max(f2+c2-2*dot,0))), masked sum over m per b
    float f2r[8];
    #pragma unroll
    for (int i = 0; i < 8; i++) f2r[i] = f2w[p * B_ + tb + 16 * i];
    float sacc[8] = {0.f, 0.f, 0.f, 0.f, 0.f, 0.f, 0.f, 0.f};
    #pragma unroll
    for (int j = 0; j < 8; j++) {
        int mm = tm + 16 * j;
        int gm = m0 + mm;
        bool valid = (gm < M_) && (mask[gm] != 0);
        float c2v = c2s[mm];
        #pragma unroll
        for (int i = 0; i < 8; i++) {
            float d2 = fmaxf(f2r[i] + c2v - 2.f * acc[i][j], 0.f);
            float e = expf(-SCALE_ * sqrtf(d2));
            if (valid) sacc[i] += e;
        }
    }
    #pragma unroll
    for (int i = 0; i < 8; i++) sred[(tb + 16 * i) * 16 + tm] = sacc[i];
    __syncthreads();
    if (t < 128) {
        float s = 0.f;
        #pragma unroll
        for (int q = 0; q < 16; q++) s += sred[t * 16 + q];
        atomicAdd(&s_neg[p * B_ + t], s);
    }
}

// ---------- final: local_loss + mmd, write scalars ----------
__global__ __launch_bounds__(512) void k_final(const float* __restrict__ s_pos,
                                               const float* __restrict__ s_neg,
                                               const double* __restrict__ mmd_part,
                                               float* out) {
    __shared__ float red[512];
    __shared__ float lp_[4];
    int t = threadIdx.x;
    float x = logf(s_pos[t]);
    float y = logf(s_neg[t]);
    red[t] = -x + y;
    __syncthreads();
    for (int s = 64; s > 0; s >>= 1) {
        if ((t & 127) < s) red[t] += red[t + s];
        __syncthreads();
    }
    if ((t & 127) == 0) {
        float l = red[t] / (float)B_;
        if (isnan(l)) l = 0.f;
        lp_[t >> 7] = l;
    }
    __syncthreads();
    if (t == 0) {
        float local_loss = (lp_[0] + lp_[1] + lp_[2] + lp_[3]) / (float)P_;
        double sxx = 0.0, syy = 0.0, sxy = 0.0;
        for (int i = 0; i < 128; i++) {
            sxx += mmd_part[i];
            syy += mmd_part[128 + i];
            sxy += mmd_part[256 + i];
        }
        double denom = 128.0 * 127.0;
        float mmd = (float)(sxx / denom + syy / denom - 2.0 * (sxy / (128.0 * 128.0)));
        out[0] = local_loss + mmd;
        out[1] = local_loss;
        out[2] = mmd;
    }
}

extern "C" void kernel_launch(void* const* d_in, const int* in_sizes, int n_in,
                              void* d_out, int out_size, void* d_ws, size_t ws_size,
                              hipStream_t stream) {
    const float* img     = (const float*)d_in[0];
    const float* txt     = (const float*)d_in[1];
    const float* local   = (const float*)d_in[2];
    const float* centers = (const float*)d_in[3];
    const int*   ci      = (const int*)d_in[4];
    const int*   pos     = (const int*)d_in[5];
    const int*   mvid    = (const int*)d_in[6];
    float* out = (float*)d_out;

    char* ws = (char*)d_ws;
    float*  img_n    = (float*)(ws + 0);
    float*  txt_n    = (float*)(ws + 65536);
    float*  a2i      = (float*)(ws + 131072);
    float*  a2t      = (float*)(ws + 131584);
    float*  f2w      = (float*)(ws + 132096);
    float*  s_pos    = (float*)(ws + 134144);
    float*  s_neg    = (float*)(ws + 136192);
    double* mmd_part = (double*)(ws + 138240);
    unsigned char* mask = (unsigned char*)(ws + 141312);

    k_init<<<(M_ + 255) / 256, 256, 0, stream>>>(mask, s_neg);
    k_scatter<<<6, 256, 0, stream>>>(ci, pos, mask);
    k_norm<<<256, 128, 0, stream>>>(img, txt, img_n, txt_n, a2i, a2t);
    k_mmd<<<128, 128, 0, stream>>>(img_n, txt_n, a2i, a2t, mmd_part);
    k_pos<<<P_ * B_, 64, 0, stream>>>(local, centers, ci, mvid, f2w, s_pos, out);
    dim3 gneg((M_ + TM_ - 1) / TM_, P_);
    k_neg<<<gneg, 256, 0, stream>>>(local, centers, f2w, mask, s_neg);
    k_final<<<1, 512, 0, stream>>>(s_pos, s_neg, mmd_part, out);
}

// Round 2
// 416.234 us; speedup vs baseline: 1.7726x; 1.7726x over previous
//
#include <hip/hip_runtime.h>
#include <math.h>

#define B_ 128
#define D_ 128
#define P_ 4
#define M_ 100000
#define K_ 10
#define SCALE_ 10.0f

typedef short bf16x8 __attribute__((ext_vector_type(8)));
typedef float floatx4 __attribute__((ext_vector_type(4)));

// fp32 -> bf16 (RNE) bit trick
__device__ inline short f2bf(float f) {
    unsigned u = __builtin_bit_cast(unsigned, f);
    unsigned r = (u + 0x7fffu + ((u >> 16) & 1u)) >> 16;
    return (short)r;
}

// ---------- reduction helpers ----------
__device__ inline float waveReduceSum(float v) {
    #pragma unroll
    for (int off = 32; off > 0; off >>= 1) v += __shfl_xor(v, off, 64);
    return v;
}

__device__ inline float blockReduce128(float v, float* sh2) {
    v = waveReduceSum(v);
    int wid = threadIdx.x >> 6;
    if ((threadIdx.x & 63) == 0) sh2[wid] = v;
    __syncthreads();
    float r = sh2[0] + sh2[1];
    __syncthreads();
    return r;
}

// ---------- init: mask=1, s_neg=0 ----------
__global__ void k_init(unsigned char* mask, float* s_neg) {
    int i = blockIdx.x * 256 + threadIdx.x;
    if (i < M_) mask[i] = 1;
    if (i < P_ * B_) s_neg[i] = 0.f;
}

// ---------- scatter zeros into mask ----------
__global__ void k_scatter(const int* __restrict__ ci, const int* __restrict__ pos,
                          unsigned char* mask) {
    int i = blockIdx.x * 256 + threadIdx.x;
    if (i < B_ * K_) mask[ci[i]] = 0;
    else if (i < B_ * K_ + B_) mask[pos[i - B_ * K_]] = 0;
}

// ---------- normalize rows of img/txt ----------
__global__ __launch_bounds__(128) void k_norm(const float* __restrict__ img,
                                              const float* __restrict__ txt,
                                              float* img_n, float* txt_n,
                                              float* a2i, float* a2t) {
    __shared__ float sh2[2];
    int row = blockIdx.x & 127, which = blockIdx.x >> 7;
    int t = threadIdx.x;
    const float* src = which ? txt : img;
    float* dst = which ? txt_n : img_n;
    float* a2  = which ? a2t : a2i;
    float v = src[row * D_ + t];
    float s = blockReduce128(v * v, sh2);
    float n = v / sqrtf(s);
    dst[row * D_ + t] = n;
    float s2 = blockReduce128(n * n, sh2);
    if (t == 0) a2[row] = s2;
}

// ---------- MMD ----------
__global__ __launch_bounds__(128) void k_mmd(const float* __restrict__ img_n,
                                             const float* __restrict__ txt_n,
                                             const float* __restrict__ a2i,
                                             const float* __restrict__ a2t,
                                             double* __restrict__ mmd_part) {
    __shared__ float ri[D_], rt[D_];
    __shared__ float sh2[2];
    int i = blockIdx.x, j = threadIdx.x;
    ri[j] = img_n[i * D_ + j];
    rt[j] = txt_n[i * D_ + j];
    __syncthreads();
    const float* aj = img_n + j * D_;
    const float* bj = txt_n + j * D_;
    float dxx = 0.f, dyy = 0.f, dxy = 0.f;
    #pragma unroll 4
    for (int d = 0; d < D_; d++) {
        float av = aj[d], bv = bj[d];
        dxx = fmaf(ri[d], av, dxx);
        dyy = fmaf(rt[d], bv, dyy);
        dxy = fmaf(ri[d], bv, dxy);
    }
    float kxx = (i == j) ? 0.f : expf(-fmaxf(a2i[i] + a2i[j] - 2.f * dxx, 0.f) * 0.5f);
    float kyy = (i == j) ? 0.f : expf(-fmaxf(a2t[i] + a2t[j] - 2.f * dyy, 0.f) * 0.5f);
    float kxy = expf(-fmaxf(a2i[i] + a2t[j] - 2.f * dxy, 0.f) * 0.5f);
    float sxx = blockReduce128(kxx, sh2);
    float syy = blockReduce128(kyy, sh2);
    float sxy = blockReduce128(kxy, sh2);
    if (j == 0) {
        mmd_part[i] = (double)sxx;
        mmd_part[128 + i] = (double)syy;
        mmd_part[256 + i] = (double)sxy;
    }
}

// ---------- pos part: one wave per (p,b); also writes f2 and pos_vid ----------
__global__ __launch_bounds__(64) void k_pos(const float* __restrict__ local,
                                            const float* __restrict__ centers,
                                            const int* __restrict__ ci,
                                            const int* __restrict__ memory_vid,
                                            float* f2w, float* s_pos, float* out) {
    int p = blockIdx.x >> 7, b = blockIdx.x & 127;
    int t = threadIdx.x;
    const float* f = local + ((size_t)p * B_ + b) * D_;
    float f0 = f[t], f1 = f[t + 64];
    float f2v = waveReduceSum(f0 * f0 + f1 * f1);
    if (t == 0) f2w[p * B_ + b] = f2v;
    float s = 0.f;
    for (int k = 0; k < K_; k++) {
        int idx = ci[b * K_ + k];
        const float* c = centers + ((size_t)p * M_ + idx) * D_;
        float c0 = c[t], c1 = c[t + 64];
        float p2 = waveReduceSum(c0 * c0 + c1 * c1);
        float fp = waveReduceSum(f0 * c0 + f1 * c1);
        float d2 = fmaxf(f2v + p2 - 2.f * fp, 0.f);
        s += expf(-SCALE_ * sqrtf(d2));
    }
    if (t == 0) s_pos[p * B_ + b] = s;
    if (p == 0 && t < K_) {
        int idx = ci[b * K_ + t];
        out[3 + b * K_ + t] = (float)memory_vid[idx];
    }
}

// ---------- neg part: bf16 MFMA GEMM, B fragments straight from global ----------
// Block: 256 threads (4 waves). Tile: 128 b x 128 m, K=128 in 4 chunks of 32.
// A (local[p], bf16) staged once in LDS in fragment order (16B/lane contiguous).
// Each wave owns 2 m-tiles of 16; per k-chunk loads B frags from global fp32
// (8 contiguous floats/lane), accumulates c2 in fp32, cvt->bf16, 16 MFMAs.
#define TM_ 128
__global__ __launch_bounds__(256, 2) void k_neg(const float* __restrict__ local,
                                                const float* __restrict__ centers,
                                                const float* __restrict__ f2w,
                                                const unsigned char* __restrict__ mask,
                                                float* __restrict__ s_neg) {
    const int p = blockIdx.y;
    const int m0 = blockIdx.x * TM_;
    const int t = threadIdx.x;
    const int w = t >> 6;        // wave 0..3
    const int l = t & 63;        // lane
    const int n16 = l & 15;      // mfma col / frag row-index
    const int q = l >> 4;        // lane quad 0..3

    __shared__ bf16x8 A_lds[2048];   // [kc][bt][lane] -> 32 KB
    __shared__ float sred[512];      // [wave][b]

    // ---- stage A = local[p] as bf16 fragments (once) ----
    const float* lp = local + (size_t)p * B_ * D_;
    #pragma unroll
    for (int s8 = 0; s8 < 8; s8++) {
        int f = t + 256 * s8;
        int fl = f & 63, bt = (f >> 6) & 7, kc = f >> 9;
        int row = bt * 16 + (fl & 15);
        int col = kc * 32 + ((fl >> 4) & 3) * 8;
        const floatx4 v0 = *(const floatx4*)(lp + row * D_ + col);
        const floatx4 v1 = *(const floatx4*)(lp + row * D_ + col + 4);
        bf16x8 fr;
        fr[0] = f2bf(v0[0]); fr[1] = f2bf(v0[1]); fr[2] = f2bf(v0[2]); fr[3] = f2bf(v0[3]);
        fr[4] = f2bf(v1[0]); fr[5] = f2bf(v1[1]); fr[6] = f2bf(v1[2]); fr[7] = f2bf(v1[3]);
        A_lds[f] = fr;
    }
    __syncthreads();

    // ---- K-loop ----
    floatx4 acc[8][2];
    #pragma unroll
    for (int bt = 0; bt < 8; bt++) {
        #pragma unroll
        for (int wm = 0; wm < 2; wm++) acc[bt][wm] = (floatx4)(0.f);
    }
    float c2a[2] = {0.f, 0.f};
    int gm[2];
    gm[0] = m0 + (w * 2 + 0) * 16 + n16;
    gm[1] = m0 + (w * 2 + 1) * 16 + n16;
    const float* cbase = centers + (size_t)p * M_ * D_;

    for (int kc = 0; kc < 4; kc++) {
        bf16x8 bfr[2];
        #pragma unroll
        for (int wm = 0; wm < 2; wm++) {
            floatx4 v0 = (floatx4)(0.f), v1 = (floatx4)(0.f);
            if (gm[wm] < M_) {
                const float* src = cbase + (size_t)gm[wm] * D_ + kc * 32 + q * 8;
                v0 = *(const floatx4*)src;
                v1 = *(const floatx4*)(src + 4);
            }
            c2a[wm] += v0[0]*v0[0] + v0[1]*v0[1] + v0[2]*v0[2] + v0[3]*v0[3]
                     + v1[0]*v1[0] + v1[1]*v1[1] + v1[2]*v1[2] + v1[3]*v1[3];
            bf16x8 fr;
            fr[0] = f2bf(v0[0]); fr[1] = f2bf(v0[1]); fr[2] = f2bf(v0[2]); fr[3] = f2bf(v0[3]);
            fr[4] = f2bf(v1[0]); fr[5] = f2bf(v1[1]); fr[6] = f2bf(v1[2]); fr[7] = f2bf(v1[3]);
            bfr[wm] = fr;
        }
        #pragma unroll
        for (int bt = 0; bt < 8; bt++) {
            bf16x8 af = A_lds[kc * 512 + bt * 64 + l];
            acc[bt][0] = __builtin_amdgcn_mfma_f32_16x16x32_bf16(af, bfr[0], acc[bt][0], 0, 0, 0);
            acc[bt][1] = __builtin_amdgcn_mfma_f32_16x16x32_bf16(af, bfr[1], acc[bt][1], 0, 0, 0);
        }
    }

    // ---- c2: reduce across lane quads (k-slices) ----
    float c2v[2], vmul[2];
    #pragma unroll
    for (int wm = 0; wm < 2; wm++) {
        float c = c2a[wm];
        c += __shfl_xor(c, 16, 64);
        c += __shfl_xor(c, 32, 64);
        c2v[wm] = c;
        vmul[wm] = (gm[wm] < M_ && mask[gm[wm] < M_ ? gm[wm] : 0] != 0) ? 1.f : 0.f;
    }

    // ---- epilogue: e = exp(-10*sqrt(max(f2+c2-2*dot,0))), masked sum over m ----
    const float* f2p = f2w + p * B_;
    #pragma unroll
    for (int bt = 0; bt < 8; bt++) {
        #pragma unroll
        for (int r = 0; r < 4; r++) {
            int b = bt * 16 + q * 4 + r;
            float f2v = f2p[b];
            float s = 0.f;
            #pragma unroll
            for (int wm = 0; wm < 2; wm++) {
                float d2 = fmaxf(f2v + c2v[wm] - 2.f * acc[bt][wm][r], 0.f);
                s += vmul[wm] * expf(-SCALE_ * sqrtf(d2));
            }
            s += __shfl_xor(s, 1, 64);
            s += __shfl_xor(s, 2, 64);
            s += __shfl_xor(s, 4, 64);
            s += __shfl_xor(s, 8, 64);
            if (n16 == 0) sred[w * 128 + b] = s;
        }
    }
    __syncthreads();
    if (t < 128) {
        float s = sred[t] + sred[128 + t] + sred[256 + t] + sred[384 + t];
        atomicAdd(&s_neg[p * B_ + t], s);
    }
}

// ---------- final ----------
__global__ __launch_bounds__(512) void k_final(const float* __restrict__ s_pos,
                                               const float* __restrict__ s_neg,
                                               const double* __restrict__ mmd_part,
                                               float* out) {
    __shared__ float red[512];
    __shared__ float lp_[4];
    int t = threadIdx.x;
    float x = logf(s_pos[t]);
    float y = logf(s_neg[t]);
    red[t] = -x + y;
    __syncthreads();
    for (int s = 64; s > 0; s >>= 1) {
        if ((t & 127) < s) red[t] += red[t + s];
        __syncthreads();
    }
    if ((t & 127) == 0) {
        float l = red[t] / (float)B_;
        if (isnan(l)) l = 0.f;
        lp_[t >> 7] = l;
    }
    __syncthreads();
    if (t == 0) {
        float local_loss = (lp_[0] + lp_[1] + lp_[2] + lp_[3]) / (float)P_;
        double sxx = 0.0, syy = 0.0, sxy = 0.0;
        for (int i = 0; i < 128; i++) {
            sxx += mmd_part[i];
            syy += mmd_part[128 + i];
            sxy += mmd_part[256 + i];
        }
        double denom = 128.0 * 127.0;
        float mmd = (float)(sxx / denom + syy / denom - 2.0 * (sxy / (128.0 * 128.0)));
        out[0] = local_loss + mmd;
        out[1] = local_loss;
        out[2] = mmd;
    }
}

extern "C" void kernel_launch(void* const* d_in, const int* in_sizes, int n_in,
                              void* d_out, int out_size, void* d_ws, size_t ws_size,
                              hipStream_t stream) {
    const float* img     = (const float*)d_in[0];
    const float* txt     = (const float*)d_in[1];
    const float* local   = (const float*)d_in[2];
    const float* centers = (const float*)d_in[3];
    const int*   ci      = (const int*)d_in[4];
    const int*   pos     = (const int*)d_in[5];
    const int*   mvid    = (const int*)d_in[6];
    float* out = (float*)d_out;

    char* ws = (char*)d_ws;
    float*  img_n    = (float*)(ws + 0);
    float*  txt_n    = (float*)(ws + 65536);
    float*  a2i      = (float*)(ws + 131072);
    float*  a2t      = (float*)(ws + 131584);
    float*  f2w      = (float*)(ws + 132096);
    float*  s_pos    = (float*)(ws + 134144);
    float*  s_neg    = (float*)(ws + 136192);
    double* mmd_part = (double*)(ws + 138240);
    unsigned char* mask = (unsigned char*)(ws + 141312);

    k_init<<<(M_ + 255) / 256, 256, 0, stream>>>(mask, s_neg);
    k_scatter<<<6, 256, 0, stream>>>(ci, pos, mask);
    k_norm<<<256, 128, 0, stream>>>(img, txt, img_n, txt_n, a2i, a2t);
    k_mmd<<<128, 128, 0, stream>>>(img_n, txt_n, a2i, a2t, mmd_part);
    k_pos<<<P_ * B_, 64, 0, stream>>>(local, centers, ci, mvid, f2w, s_pos, out);
    dim3 gneg((M_ + TM_ - 1) / TM_, P_);
    k_neg<<<gneg, 256, 0, stream>>>(local, centers, f2w, mask, s_neg);
    k_final<<<1, 512, 0, stream>>>(s_pos, s_neg, mmd_part, out);
}

// Round 3
// 379.529 us; speedup vs baseline: 1.9441x; 1.0967x over previous
//
#include <hip/hip_runtime.h>
#include <math.h>

#define B_ 128
#define D_ 128
#define P_ 4
#define M_ 100000
#define K_ 10
#define SCALE_ 10.0f

typedef short bf16x8 __attribute__((ext_vector_type(8)));
typedef float floatx4 __attribute__((ext_vector_type(4)));

// pack two fp32 -> two bf16 (truncate) in one v_perm_b32
__device__ inline unsigned pack_bf16_trunc(unsigned f0, unsigned f1) {
    return __builtin_amdgcn_perm(f1, f0, 0x07060302u);
}

// ---------- reduction helpers ----------
__device__ inline float waveReduceSum(float v) {
    #pragma unroll
    for (int off = 32; off > 0; off >>= 1) v += __shfl_xor(v, off, 64);
    return v;
}

__device__ inline float blockReduce128(float v, float* sh2) {
    v = waveReduceSum(v);
    int wid = threadIdx.x >> 6;
    if ((threadIdx.x & 63) == 0) sh2[wid] = v;
    __syncthreads();
    float r = sh2[0] + sh2[1];
    __syncthreads();
    return r;
}

// ---------- normalize rows of img/txt; also zero s_neg ----------
__global__ __launch_bounds__(128) void k_norm(const float* __restrict__ img,
                                              const float* __restrict__ txt,
                                              float* img_n, float* txt_n,
                                              float* a2i, float* a2t,
                                              float* s_neg) {
    __shared__ float sh2[2];
    int row = blockIdx.x & 127, which = blockIdx.x >> 7;
    int t = threadIdx.x;
    if (blockIdx.x < 4) s_neg[blockIdx.x * 128 + t] = 0.f;
    const float* src = which ? txt : img;
    float* dst = which ? txt_n : img_n;
    float* a2  = which ? a2t : a2i;
    float v = src[row * D_ + t];
    float s = blockReduce128(v * v, sh2);
    float n = v / sqrtf(s);
    dst[row * D_ + t] = n;
    float s2 = blockReduce128(n * n, sh2);
    if (t == 0) a2[row] = s2;
}

// ---------- MMD ----------
__global__ __launch_bounds__(128) void k_mmd(const float* __restrict__ img_n,
                                             const float* __restrict__ txt_n,
                                             const float* __restrict__ a2i,
                                             const float* __restrict__ a2t,
                                             double* __restrict__ mmd_part) {
    __shared__ float ri[D_], rt[D_];
    __shared__ float sh2[2];
    int i = blockIdx.x, j = threadIdx.x;
    ri[j] = img_n[i * D_ + j];
    rt[j] = txt_n[i * D_ + j];
    __syncthreads();
    const float* aj = img_n + j * D_;
    const float* bj = txt_n + j * D_;
    float dxx = 0.f, dyy = 0.f, dxy = 0.f;
    #pragma unroll 4
    for (int d = 0; d < D_; d++) {
        float av = aj[d], bv = bj[d];
        dxx = fmaf(ri[d], av, dxx);
        dyy = fmaf(rt[d], bv, dyy);
        dxy = fmaf(ri[d], bv, dxy);
    }
    float kxx = (i == j) ? 0.f : expf(-fmaxf(a2i[i] + a2i[j] - 2.f * dxx, 0.f) * 0.5f);
    float kyy = (i == j) ? 0.f : expf(-fmaxf(a2t[i] + a2t[j] - 2.f * dyy, 0.f) * 0.5f);
    float kxy = expf(-fmaxf(a2i[i] + a2t[j] - 2.f * dxy, 0.f) * 0.5f);
    float sxx = blockReduce128(kxx, sh2);
    float syy = blockReduce128(kyy, sh2);
    float sxy = blockReduce128(kxy, sh2);
    if (j == 0) {
        mmd_part[i] = (double)sxx;
        mmd_part[128 + i] = (double)syy;
        mmd_part[256 + i] = (double)sxy;
    }
}

// ---------- pos part: one wave per (p,b); also writes f2 and pos_vid ----------
__global__ __launch_bounds__(64) void k_pos(const float* __restrict__ local,
                                            const float* __restrict__ centers,
                                            const int* __restrict__ ci,
                                            const int* __restrict__ memory_vid,
                                            float* f2w, float* s_pos, float* out) {
    int p = blockIdx.x >> 7, b = blockIdx.x & 127;
    int t = threadIdx.x;
    const float* f = local + ((size_t)p * B_ + b) * D_;
    float f0 = f[t], f1 = f[t + 64];
    float f2v = waveReduceSum(f0 * f0 + f1 * f1);
    if (t == 0) f2w[p * B_ + b] = f2v;
    float s = 0.f;
    for (int k = 0; k < K_; k++) {
        int idx = ci[b * K_ + k];
        const float* c = centers + ((size_t)p * M_ + idx) * D_;
        float c0 = c[t], c1 = c[t + 64];
        float p2 = waveReduceSum(c0 * c0 + c1 * c1);
        float fp = waveReduceSum(f0 * c0 + f1 * c1);
        float d2 = fmaxf(f2v + p2 - 2.f * fp, 0.f);
        s += expf(-SCALE_ * sqrtf(d2));
    }
    if (t == 0) s_pos[p * B_ + b] = s;
    if (p == 0 && t < K_) {
        int idx = ci[b * K_ + t];
        out[3 + b * K_ + t] = (float)memory_vid[idx];
    }
}

// ---------- neg part: bf16 MFMA, all-K upfront B loads, in-LDS mask ----------
// Block: 256 threads (4 waves). Tile: 128 b x 128 m, K=128.
// A (local[p]) staged once in LDS in fragment order. Each wave owns 2 m-tiles;
// issues all 16 B loads (16 KB in flight), perm-packs to bf16, 32 MFMAs,
// fused masked-exp epilogue. Mask built per-block in LDS from ci/pos.
#define TM_ 128
__global__ __launch_bounds__(256, 3) void k_neg(const float* __restrict__ local,
                                                const float* __restrict__ centers,
                                                const float* __restrict__ f2w,
                                                const int* __restrict__ ci,
                                                const int* __restrict__ pos,
                                                float* __restrict__ s_neg) {
    const int p = blockIdx.y;
    const int m0 = blockIdx.x * TM_;
    const int t = threadIdx.x;
    const int w = t >> 6;        // wave 0..3
    const int l = t & 63;        // lane
    const int n16 = l & 15;      // row/col within 16-tile
    const int q = l >> 4;        // lane quad 0..3

    __shared__ bf16x8 A_lds[2048];     // 32 KB, fragment order
    __shared__ float sred[512];
    __shared__ unsigned char msk[TM_];

    // ---- stage A = local[p] as bf16 fragments; init msk ----
    const float* lp = local + (size_t)p * B_ * D_;
    #pragma unroll
    for (int s8 = 0; s8 < 8; s8++) {
        int f = t + 256 * s8;
        int fl = f & 63, bt = (f >> 6) & 7, kc = f >> 9;
        int row = bt * 16 + (fl & 15);
        int col = kc * 32 + ((fl >> 4) & 3) * 8;
        const uint4 u0 = *(const uint4*)(lp + row * D_ + col);
        const uint4 u1 = *(const uint4*)(lp + row * D_ + col + 4);
        union { bf16x8 v; unsigned u[4]; } fr;
        fr.u[0] = pack_bf16_trunc(u0.x, u0.y);
        fr.u[1] = pack_bf16_trunc(u0.z, u0.w);
        fr.u[2] = pack_bf16_trunc(u1.x, u1.y);
        fr.u[3] = pack_bf16_trunc(u1.z, u1.w);
        A_lds[f] = fr.v;
    }
    if (t < TM_) msk[t] = 1;
    __syncthreads();

    // ---- issue ALL B loads for this wave's 2 m-tiles (16 x 16B in flight) ----
    int gm[2];
    gm[0] = m0 + (w * 2 + 0) * 16 + n16;
    gm[1] = m0 + (w * 2 + 1) * 16 + n16;
    const float* cb = centers + (size_t)p * M_ * D_;
    uint4 rb[2][4][2];
    if (m0 + TM_ <= M_) {
        #pragma unroll
        for (int wm = 0; wm < 2; wm++) {
            const uint4* src = (const uint4*)(cb + (size_t)gm[wm] * D_ + q * 8);
            #pragma unroll
            for (int kc = 0; kc < 4; kc++) {
                rb[wm][kc][0] = src[kc * 8];
                rb[wm][kc][1] = src[kc * 8 + 1];
            }
        }
    } else {
        const uint4 z = make_uint4(0u, 0u, 0u, 0u);
        #pragma unroll
        for (int wm = 0; wm < 2; wm++) {
            const uint4* src = (const uint4*)(cb + (size_t)gm[wm] * D_ + q * 8);
            #pragma unroll
            for (int kc = 0; kc < 4; kc++) {
                if (gm[wm] < M_) {
                    rb[wm][kc][0] = src[kc * 8];
                    rb[wm][kc][1] = src[kc * 8 + 1];
                } else {
                    rb[wm][kc][0] = z;
                    rb[wm][kc][1] = z;
                }
            }
        }
    }

    // ---- scatter mask zeros (L2-hot; overlaps with load latency) ----
    #pragma unroll
    for (int i = 0; i < 5; i++) {                 // 5*256 = B_*K_ = 1280
        int idx = ci[t + 256 * i];
        unsigned r = (unsigned)(idx - m0);
        if (r < TM_) msk[r] = 0;
    }
    if (t < B_) {
        unsigned r = (unsigned)(pos[t] - m0);
        if (r < TM_) msk[r] = 0;
    }

    // ---- c2 + convert to bf16 fragments ----
    float c2a[2];
    bf16x8 bfr[2][4];
    #pragma unroll
    for (int wm = 0; wm < 2; wm++) {
        float c = 0.f;
        #pragma unroll
        for (int kc = 0; kc < 4; kc++) {
            union { uint4 u; floatx4 f; } a, b;
            a.u = rb[wm][kc][0];
            b.u = rb[wm][kc][1];
            c += a.f[0]*a.f[0] + a.f[1]*a.f[1] + a.f[2]*a.f[2] + a.f[3]*a.f[3]
               + b.f[0]*b.f[0] + b.f[1]*b.f[1] + b.f[2]*b.f[2] + b.f[3]*b.f[3];
            union { bf16x8 v; unsigned u[4]; } fr;
            fr.u[0] = pack_bf16_trunc(a.u.x, a.u.y);
            fr.u[1] = pack_bf16_trunc(a.u.z, a.u.w);
            fr.u[2] = pack_bf16_trunc(b.u.x, b.u.y);
            fr.u[3] = pack_bf16_trunc(b.u.z, b.u.w);
            bfr[wm][kc] = fr.v;
        }
        c2a[wm] = c;
    }

    // ---- MFMA: 8 b-tiles x 2 m-tiles x 4 kc ----
    floatx4 acc[8][2];
    #pragma unroll
    for (int bt = 0; bt < 8; bt++) {
        acc[bt][0] = (floatx4)(0.f);
        acc[bt][1] = (floatx4)(0.f);
    }
    #pragma unroll
    for (int kc = 0; kc < 4; kc++) {
        #pragma unroll
        for (int bt = 0; bt < 8; bt++) {
            bf16x8 af = A_lds[kc * 512 + bt * 64 + l];
            acc[bt][0] = __builtin_amdgcn_mfma_f32_16x16x32_bf16(af, bfr[0][kc], acc[bt][0], 0, 0, 0);
            acc[bt][1] = __builtin_amdgcn_mfma_f32_16x16x32_bf16(af, bfr[1][kc], acc[bt][1], 0, 0, 0);
        }
    }

    // ---- c2 reduce across lane quads ----
    float c2v[2], vmul[2];
    #pragma unroll
    for (int wm = 0; wm < 2; wm++) {
        float c = c2a[wm];
        c += __shfl_xor(c, 16, 64);
        c += __shfl_xor(c, 32, 64);
        c2v[wm] = c;
        vmul[wm] = (gm[wm] < M_ && msk[(w * 2 + wm) * 16 + n16] != 0) ? 1.f : 0.f;
    }

    // ---- epilogue: e = exp(-10*sqrt(max(f2+c2-2*dot,0))), masked sum over m ----
    const float* f2p = f2w + p * B_;
    #pragma unroll
    for (int bt = 0; bt < 8; bt++) {
        #pragma unroll
        for (int r = 0; r < 4; r++) {
            int b = bt * 16 + q * 4 + r;
            float f2v = f2p[b];
            float s = 0.f;
            #pragma unroll
            for (int wm = 0; wm < 2; wm++) {
                float d2 = fmaxf(f2v + c2v[wm] - 2.f * acc[bt][wm][r], 0.f);
                s += vmul[wm] * expf(-SCALE_ * sqrtf(d2));
            }
            s += __shfl_xor(s, 1, 64);
            s += __shfl_xor(s, 2, 64);
            s += __shfl_xor(s, 4, 64);
            s += __shfl_xor(s, 8, 64);
            if (n16 == 0) sred[w * 128 + b] = s;
        }
    }
    __syncthreads();
    if (t < 128) {
        float s = sred[t] + sred[128 + t] + sred[256 + t] + sred[384 + t];
        atomicAdd(&s_neg[p * B_ + t], s);
    }
}

// ---------- final ----------
__global__ __launch_bounds__(512) void k_final(const float* __restrict__ s_pos,
                                               const float* __restrict__ s_neg,
                                               const double* __restrict__ mmd_part,
                                               float* out) {
    __shared__ float red[512];
    __shared__ float lp_[4];
    int t = threadIdx.x;
    float x = logf(s_pos[t]);
    float y = logf(s_neg[t]);
    red[t] = -x + y;
    __syncthreads();
    for (int s = 64; s > 0; s >>= 1) {
        if ((t & 127) < s) red[t] += red[t + s];
        __syncthreads();
    }
    if ((t & 127) == 0) {
        float l = red[t] / (float)B_;
        if (isnan(l)) l = 0.f;
        lp_[t >> 7] = l;
    }
    __syncthreads();
    if (t == 0) {
        float local_loss = (lp_[0] + lp_[1] + lp_[2] + lp_[3]) / (float)P_;
        double sxx = 0.0, syy = 0.0, sxy = 0.0;
        for (int i = 0; i < 128; i++) {
            sxx += mmd_part[i];
            syy += mmd_part[128 + i];
            sxy += mmd_part[256 + i];
        }
        double denom = 128.0 * 127.0;
        float mmd = (float)(sxx / denom + syy / denom - 2.0 * (sxy / (128.0 * 128.0)));
        out[0] = local_loss + mmd;
        out[1] = local_loss;
        out[2] = mmd;
    }
}

extern "C" void kernel_launch(void* const* d_in, const int* in_sizes, int n_in,
                              void* d_out, int out_size, void* d_ws, size_t ws_size,
                              hipStream_t stream) {
    const float* img     = (const float*)d_in[0];
    const float* txt     = (const float*)d_in[1];
    const float* local   = (const float*)d_in[2];
    const float* centers = (const float*)d_in[3];
    const int*   ci      = (const int*)d_in[4];
    const int*   pos     = (const int*)d_in[5];
    const int*   mvid    = (const int*)d_in[6];
    float* out = (float*)d_out;

    char* ws = (char*)d_ws;
    float*  img_n    = (float*)(ws + 0);
    float*  txt_n    = (float*)(ws + 65536);
    float*  a2i      = (float*)(ws + 131072);
    float*  a2t      = (float*)(ws + 131584);
    float*  f2w      = (float*)(ws + 132096);
    float*  s_pos    = (float*)(ws + 134144);
    float*  s_neg    = (float*)(ws + 136192);
    double* mmd_part = (double*)(ws + 138240);

    k_norm<<<256, 128, 0, stream>>>(img, txt, img_n, txt_n, a2i, a2t, s_neg);
    k_mmd<<<128, 128, 0, stream>>>(img_n, txt_n, a2i, a2t, mmd_part);
    k_pos<<<P_ * B_, 64, 0, stream>>>(local, centers, ci, mvid, f2w, s_pos, out);
    dim3 gneg((M_ + TM_ - 1) / TM_, P_);
    k_neg<<<gneg, 256, 0, stream>>>(local, centers, f2w, ci, pos, s_neg);
    k_final<<<1, 512, 0, stream>>>(s_pos, s_neg, mmd_part, out);
}

// Round 4
// 345.495 us; speedup vs baseline: 2.1356x; 1.0985x over previous
//
#include <hip/hip_runtime.h>
#include <math.h>

#define B_ 128
#define D_ 128
#define P_ 4
#define M_ 100000
#define K_ 10
#define SCALE_ 10.0f
#define MB_ 782                 // ceil(100000/128)
#define NEG_BLOCKS (MB_ * P_)   // 3128
#define MMD_BLOCKS 128
#define POS_BLOCKS 128          // 512 (p,b) pairs / 4 waves
#define D2_CUT 120.0f           // d2 >= 120 -> exp(-10*sqrt(d2)) == 0.0f exactly (2^-158)

typedef short bf16x8 __attribute__((ext_vector_type(8)));
typedef float floatx4 __attribute__((ext_vector_type(4)));

// pack two fp32 -> two bf16 (truncate) in one v_perm_b32
__device__ inline unsigned pack_bf16_trunc(unsigned f0, unsigned f1) {
    return __builtin_amdgcn_perm(f1, f0, 0x07060302u);
}

// ---------- cross-lane helpers ----------
// DPP add: xor1=quad_perm[1,0,3,2]=0xB1, xor2=quad_perm[2,3,0,1]=0x4E,
// xor7=row_half_mirror=0x141, xor15=row_mirror=0x140  (all VALU, no LDS pipe)
template <int CTRL>
__device__ inline float dpp_add(float v) {
    int x = __builtin_amdgcn_update_dpp(0, __builtin_bit_cast(int, v), CTRL, 0xF, 0xF, true);
    return v + __builtin_bit_cast(float, x);
}
__device__ inline float row16Sum(float v) {          // sum over lanes sharing l>>4
    v = dpp_add<0xB1>(v);
    v = dpp_add<0x4E>(v);
    v = dpp_add<0x141>(v);
    v = dpp_add<0x140>(v);
    return v;
}
__device__ inline float waveSum64(float v) {
    v = row16Sum(v);
    v += __shfl_xor(v, 16, 64);
    v += __shfl_xor(v, 32, 64);
    return v;
}
// legacy shfl butterfly (kept for mmd path: preserves round-3 summation order)
__device__ inline float waveReduceSumOld(float v) {
    #pragma unroll
    for (int off = 32; off > 0; off >>= 1) v += __shfl_xor(v, off, 64);
    return v;
}
__device__ inline float blockReduce128(float v, float* sh2) {  // 128-thread blocks
    v = waveSum64(v);
    int wid = threadIdx.x >> 6;
    if ((threadIdx.x & 63) == 0) sh2[wid] = v;
    __syncthreads();
    float r = sh2[0] + sh2[1];
    __syncthreads();
    return r;
}

// ---------- kernel A: normalize (transposed out) + f2 + zero s_neg ----------
// grid 768 x 128: bid<256 -> norm rows; bid in [256,768) -> f2 of local rows
__global__ __launch_bounds__(128) void k_prep(const float* __restrict__ img,
                                              const float* __restrict__ txt,
                                              const float* __restrict__ local,
                                              float* imgT, float* txtT,
                                              float* a2i, float* a2t,
                                              float* f2w, float* s_neg) {
    __shared__ float sh2[2];
    int bid = blockIdx.x, t = threadIdx.x;
    if (bid < 256) {
        int row = bid & 127, which = bid >> 7;
        if (bid < 4) s_neg[bid * 128 + t] = 0.f;
        const float* src = which ? txt : img;
        float* dstT = which ? txtT : imgT;
        float* a2 = which ? a2t : a2i;
        float v = src[row * D_ + t];
        float s = blockReduce128(v * v, sh2);
        float n = v / sqrtf(s);
        dstT[t * 128 + row] = n;                  // transposed for coalesced mmd stream
        float s2 = blockReduce128(n * n, sh2);
        if (t == 0) a2[row] = s2;
    } else {
        int r = bid - 256;                        // 0..511 = (p,b)
        float v = local[(size_t)r * D_ + t];
        float s = blockReduce128(v * v, sh2);
        if (t == 0) f2w[r] = s;
    }
}

// ---------- kernel B: fused neg (MFMA) + mmd + pos ----------
__global__ __launch_bounds__(256, 4) void k_main(const float* __restrict__ local,
                                                 const float* __restrict__ centers,
                                                 const float* __restrict__ imgT,
                                                 const float* __restrict__ txtT,
                                                 const float* __restrict__ a2i,
                                                 const float* __restrict__ a2t,
                                                 const int* __restrict__ ci,
                                                 const int* __restrict__ posi,
                                                 const int* __restrict__ mvid,
                                                 const float* __restrict__ f2w,
                                                 float* __restrict__ s_neg,
                                                 float* __restrict__ s_pos,
                                                 double* __restrict__ mmd_part,
                                                 float* __restrict__ out) {
    union Smem {
        struct {
            bf16x8 A_lds[2048];     // 32 KB, fragment order
            float sred[512];
            float f2l[128];
            unsigned char msk[128];
        } n;
        struct {
            float ri[128], rt[128];
            float sh2[2];
        } m;
    };
    __shared__ Smem sm;
    const int bid = blockIdx.x;
    const int t = threadIdx.x;
    const int w = t >> 6;
    const int l = t & 63;

    if (bid < NEG_BLOCKS) {
        // ================= neg =================
        const int p = bid / MB_;
        const int mb = bid - p * MB_;
        const int m0 = mb * 128;
        const int n16 = l & 15;
        const int q = l >> 4;

        // ---- stage A = local[p] as bf16 fragments; msk init; f2 to LDS ----
        const float* lp = local + (size_t)p * B_ * D_;
        if (t < 128) { sm.n.msk[t] = 1; sm.n.f2l[t] = f2w[p * 128 + t]; }
        #pragma unroll
        for (int s8 = 0; s8 < 8; s8++) {
            int f = t + 256 * s8;
            int fl = f & 63, bt = (f >> 6) & 7, kc = f >> 9;
            int row = bt * 16 + (fl & 15);
            int col = kc * 32 + ((fl >> 4) & 3) * 8;
            const uint4 u0 = *(const uint4*)(lp + row * D_ + col);
            const uint4 u1 = *(const uint4*)(lp + row * D_ + col + 4);
            union { bf16x8 v; unsigned u[4]; } fr;
            fr.u[0] = pack_bf16_trunc(u0.x, u0.y);
            fr.u[1] = pack_bf16_trunc(u0.z, u0.w);
            fr.u[2] = pack_bf16_trunc(u1.x, u1.y);
            fr.u[3] = pack_bf16_trunc(u1.z, u1.w);
            sm.n.A_lds[f] = fr.v;
        }
        __syncthreads();

        // ---- issue ALL B loads (16 x 16B in flight per thread) ----
        int gm[2];
        gm[0] = m0 + (w * 2 + 0) * 16 + n16;
        gm[1] = m0 + (w * 2 + 1) * 16 + n16;
        const float* cb = centers + (size_t)p * M_ * D_;
        uint4 rb[2][4][2];
        if (m0 + 128 <= M_) {
            #pragma unroll
            for (int wm = 0; wm < 2; wm++) {
                const uint4* src = (const uint4*)(cb + (size_t)gm[wm] * D_ + q * 8);
                #pragma unroll
                for (int kc = 0; kc < 4; kc++) {
                    rb[wm][kc][0] = src[kc * 8];
                    rb[wm][kc][1] = src[kc * 8 + 1];
                }
            }
        } else {
            const uint4 z = make_uint4(0u, 0u, 0u, 0u);
            #pragma unroll
            for (int wm = 0; wm < 2; wm++) {
                const uint4* src = (const uint4*)(cb + (size_t)gm[wm] * D_ + q * 8);
                #pragma unroll
                for (int kc = 0; kc < 4; kc++) {
                    if (gm[wm] < M_) {
                        rb[wm][kc][0] = src[kc * 8];
                        rb[wm][kc][1] = src[kc * 8 + 1];
                    } else {
                        rb[wm][kc][0] = z;
                        rb[wm][kc][1] = z;
                    }
                }
            }
        }

        // ---- scatter mask zeros (overlaps load latency) ----
        #pragma unroll
        for (int i = 0; i < 5; i++) {             // 5*256 = B_*K_
            int idx = ci[t + 256 * i];
            unsigned r = (unsigned)(idx - m0);
            if (r < 128u) sm.n.msk[r] = 0;
        }
        if (t < B_) {
            unsigned r = (unsigned)(posi[t] - m0);
            if (r < 128u) sm.n.msk[r] = 0;
        }
        __syncthreads();   // msk scatter visible before epilogue reads (r3 latent race fix)

        // ---- c2 + convert to bf16 fragments ----
        float c2a[2];
        bf16x8 bfr[2][4];
        #pragma unroll
        for (int wm = 0; wm < 2; wm++) {
            float c = 0.f;
            #pragma unroll
            for (int kc = 0; kc < 4; kc++) {
                union { uint4 u; floatx4 f; } a, b;
                a.u = rb[wm][kc][0];
                b.u = rb[wm][kc][1];
                c += a.f[0]*a.f[0] + a.f[1]*a.f[1] + a.f[2]*a.f[2] + a.f[3]*a.f[3]
                   + b.f[0]*b.f[0] + b.f[1]*b.f[1] + b.f[2]*b.f[2] + b.f[3]*b.f[3];
                union { bf16x8 v; unsigned u[4]; } fr;
                fr.u[0] = pack_bf16_trunc(a.u.x, a.u.y);
                fr.u[1] = pack_bf16_trunc(a.u.z, a.u.w);
                fr.u[2] = pack_bf16_trunc(b.u.x, b.u.y);
                fr.u[3] = pack_bf16_trunc(b.u.z, b.u.w);
                bfr[wm][kc] = fr.v;
            }
            c2a[wm] = c;
        }

        // ---- MFMA ----
        floatx4 acc[8][2];
        #pragma unroll
        for (int bt = 0; bt < 8; bt++) { acc[bt][0] = (floatx4)(0.f); acc[bt][1] = (floatx4)(0.f); }
        #pragma unroll
        for (int kc = 0; kc < 4; kc++) {
            #pragma unroll
            for (int bt = 0; bt < 8; bt++) {
                bf16x8 af = sm.n.A_lds[kc * 512 + bt * 64 + l];
                acc[bt][0] = __builtin_amdgcn_mfma_f32_16x16x32_bf16(af, bfr[0][kc], acc[bt][0], 0, 0, 0);
                acc[bt][1] = __builtin_amdgcn_mfma_f32_16x16x32_bf16(af, bfr[1][kc], acc[bt][1], 0, 0, 0);
            }
        }

        // ---- c2 reduce across lane quads ----
        float c2v[2];
        #pragma unroll
        for (int wm = 0; wm < 2; wm++) {
            float c = c2a[wm];
            c += __shfl_xor(c, 16, 64);
            c += __shfl_xor(c, 32, 64);
            c2v[wm] = c;
        }

        // ---- epilogue: underflow-vote fast path ----
        float dmin = 1e30f;
        #pragma unroll
        for (int bt = 0; bt < 8; bt++) {
            floatx4 f4 = *(const floatx4*)&sm.n.f2l[bt * 16 + q * 4];
            #pragma unroll
            for (int r = 0; r < 4; r++) {
                float d20 = fmaf(-2.f, acc[bt][0][r], f4[r] + c2v[0]);
                float d21 = fmaf(-2.f, acc[bt][1][r], f4[r] + c2v[1]);
                dmin = fminf(dmin, fminf(d20, d21));
            }
        }
        if (!__any(dmin < D2_CUT)) {
            // all 64 contributions underflow to exactly 0.0f (d2>=120 -> e<2^-158)
            sm.n.sred[w * 128 + l] = 0.f;
            sm.n.sred[w * 128 + l + 64] = 0.f;
        } else {
            // faithful slow path (cold)
            float vm0 = (gm[0] < M_ && sm.n.msk[(w * 2 + 0) * 16 + n16] != 0) ? 1.f : 0.f;
            float vm1 = (gm[1] < M_ && sm.n.msk[(w * 2 + 1) * 16 + n16] != 0) ? 1.f : 0.f;
            #pragma unroll
            for (int bt = 0; bt < 8; bt++) {
                floatx4 f4 = *(const floatx4*)&sm.n.f2l[bt * 16 + q * 4];
                #pragma unroll
                for (int r = 0; r < 4; r++) {
                    float s = 0.f;
                    float d20 = fmaxf(fmaf(-2.f, acc[bt][0][r], f4[r] + c2v[0]), 0.f);
                    float d21 = fmaxf(fmaf(-2.f, acc[bt][1][r], f4[r] + c2v[1]), 0.f);
                    if (d20 < D2_CUT) s += vm0 * expf(-SCALE_ * sqrtf(d20));
                    if (d21 < D2_CUT) s += vm1 * expf(-SCALE_ * sqrtf(d21));
                    s = row16Sum(s);
                    if (n16 == 0) sm.n.sred[w * 128 + bt * 16 + q * 4 + r] = s;
                }
            }
        }
        __syncthreads();
        if (t < 128) {
            float s = sm.n.sred[t] + sm.n.sred[128 + t] + sm.n.sred[256 + t] + sm.n.sred[384 + t];
            atomicAdd(&s_neg[p * 128 + t], s);
        }
    } else if (bid < NEG_BLOCKS + MMD_BLOCKS) {
        // ================= mmd (row i); threads 0-127 active, coalesced stream =================
        const int i = bid - NEG_BLOCKS;
        if (t < 128) {
            sm.m.ri[t] = imgT[t * 128 + i];      // row i gather (once)
            sm.m.rt[t] = txtT[t * 128 + i];
        }
        __syncthreads();
        float kxx = 0.f, kyy = 0.f, kxy = 0.f;
        if (t < 128) {
            float dxx = 0.f, dyy = 0.f, dxy = 0.f;
            #pragma unroll 4
            for (int d = 0; d < D_; d++) {
                float rid = sm.m.ri[d], rtd = sm.m.rt[d];
                float av = imgT[d * 128 + t];    // coalesced
                float bv = txtT[d * 128 + t];
                dxx = fmaf(rid, av, dxx);
                dyy = fmaf(rtd, bv, dyy);
                dxy = fmaf(rid, bv, dxy);
            }
            kxx = (i == t) ? 0.f : expf(-fmaxf(a2i[i] + a2i[t] - 2.f * dxx, 0.f) * 0.5f);
            kyy = (i == t) ? 0.f : expf(-fmaxf(a2t[i] + a2t[t] - 2.f * dyy, 0.f) * 0.5f);
            kxy = expf(-fmaxf(a2i[i] + a2t[t] - 2.f * dxy, 0.f) * 0.5f);
        }
        // same reduction tree as round 3 (shfl butterfly + 2-slot combine)
        float sxx = waveReduceSumOld(kxx);
        float syy = waveReduceSumOld(kyy);
        float sxy = waveReduceSumOld(kxy);
        __syncthreads();
        if (t == 0)  { sm.m.sh2[0] = sxx; }
        if (t == 64) { sm.m.sh2[1] = sxx; }
        __syncthreads();
        float txx = sm.m.sh2[0] + sm.m.sh2[1];
        __syncthreads();
        if (t == 0)  { sm.m.sh2[0] = syy; }
        if (t == 64) { sm.m.sh2[1] = syy; }
        __syncthreads();
        float tyy = sm.m.sh2[0] + sm.m.sh2[1];
        __syncthreads();
        if (t == 0)  { sm.m.sh2[0] = sxy; }
        if (t == 64) { sm.m.sh2[1] = sxy; }
        __syncthreads();
        float txy = sm.m.sh2[0] + sm.m.sh2[1];
        if (t == 0) {
            mmd_part[i] = (double)txx;
            mmd_part[128 + i] = (double)tyy;
            mmd_part[256 + i] = (double)txy;
        }
    } else {
        // ================= pos: one wave per (p,b), 4 per block =================
        const int pair = (bid - (NEG_BLOCKS + MMD_BLOCKS)) * 4 + w;  // 0..511
        const int p = pair >> 7, b = pair & 127;
        const float* f = local + (size_t)pair * D_;
        float f0 = f[l], f1 = f[l + 64];
        float f2v = f2w[pair];
        const float* cb = centers + (size_t)p * M_ * D_;
        float s = 0.f;
        #pragma unroll
        for (int k = 0; k < K_; k++) {
            int idx = ci[b * K_ + k];
            const float* c = cb + (size_t)idx * D_;
            float c0 = c[l], c1 = c[l + 64];
            float p2 = waveSum64(c0 * c0 + c1 * c1);
            float fp = waveSum64(f0 * c0 + f1 * c1);
            float d2 = fmaxf(f2v + p2 - 2.f * fp, 0.f);
            if (d2 < D2_CUT) s += expf(-SCALE_ * sqrtf(d2));   // wave-uniform branch
        }
        if (l == 0) s_pos[pair] = s;
        if (p == 0 && l < K_) {
            int ix = ci[b * K_ + l];
            out[3 + b * K_ + l] = (float)mvid[ix];
        }
    }
}

// ---------- kernel C: final scalars ----------
__global__ __launch_bounds__(512) void k_final(const float* __restrict__ s_pos,
                                               const float* __restrict__ s_neg,
                                               const double* __restrict__ mmd_part,
                                               float* out) {
    __shared__ float red[512];
    __shared__ float lp_[4];
    int t = threadIdx.x;
    float x = logf(s_pos[t]);
    float y = logf(s_neg[t]);
    red[t] = -x + y;
    __syncthreads();
    for (int s = 64; s > 0; s >>= 1) {
        if ((t & 127) < s) red[t] += red[t + s];
        __syncthreads();
    }
    if ((t & 127) == 0) {
        float lv = red[t] / (float)B_;
        if (isnan(lv)) lv = 0.f;
        lp_[t >> 7] = lv;
    }
    __syncthreads();
    if (t == 0) {
        float local_loss = (lp_[0] + lp_[1] + lp_[2] + lp_[3]) / (float)P_;
        double sxx = 0.0, syy = 0.0, sxy = 0.0;
        for (int i = 0; i < 128; i++) {
            sxx += mmd_part[i];
            syy += mmd_part[128 + i];
            sxy += mmd_part[256 + i];
        }
        double denom = 128.0 * 127.0;
        float mmd = (float)(sxx / denom + syy / denom - 2.0 * (sxy / (128.0 * 128.0)));
        out[0] = local_loss + mmd;
        out[1] = local_loss;
        out[2] = mmd;
    }
}

extern "C" void kernel_launch(void* const* d_in, const int* in_sizes, int n_in,
                              void* d_out, int out_size, void* d_ws, size_t ws_size,
                              hipStream_t stream) {
    const float* img     = (const float*)d_in[0];
    const float* txt     = (const float*)d_in[1];
    const float* local   = (const float*)d_in[2];
    const float* centers = (const float*)d_in[3];
    const int*   ci      = (const int*)d_in[4];
    const int*   posi    = (const int*)d_in[5];
    const int*   mvid    = (const int*)d_in[6];
    float* out = (float*)d_out;

    char* ws = (char*)d_ws;
    float*  imgT     = (float*)(ws + 0);
    float*  txtT     = (float*)(ws + 65536);
    float*  a2i      = (float*)(ws + 131072);
    float*  a2t      = (float*)(ws + 131584);
    float*  f2w      = (float*)(ws + 132096);
    float*  s_pos    = (float*)(ws + 134144);
    float*  s_neg    = (float*)(ws + 136192);
    double* mmd_part = (double*)(ws + 138240);

    k_prep<<<768, 128, 0, stream>>>(img, txt, local, imgT, txtT, a2i, a2t, f2w, s_neg);
    k_main<<<NEG_BLOCKS + MMD_BLOCKS + POS_BLOCKS, 256, 0, stream>>>(
        local, centers, imgT, txtT, a2i, a2t, ci, posi, mvid, f2w,
        s_neg, s_pos, mmd_part, out);
    k_final<<<1, 512, 0, stream>>>(s_pos, s_neg, mmd_part, out);
}